// Round 6
// baseline (269.923 us; speedup 1.0000x reference)
//
#include <hip/hip_runtime.h>
#include <hip/hip_bf16.h>
#include <cstddef>
#include <cstdint>

#define BS   16
#define SLEN 512
#define DM   512
#define NH   8
#define DK   64
#define DC   21

typedef __attribute__((ext_vector_type(8))) short short8;   // 8 bf16 = 4 VGPR
typedef __attribute__((ext_vector_type(4))) float f32x4;
typedef __attribute__((ext_vector_type(4))) _Float16 h16x4; // 4 fp16 = 8B

__device__ inline unsigned pack_bf16(float a, float b) {
    unsigned ua = __builtin_bit_cast(unsigned, a);
    unsigned ub = __builtin_bit_cast(unsigned, b);
    ua = (ua + 0x7fffu + ((ua >> 16) & 1u)) >> 16;          // RNE
    ub = (ub + 0x7fffu + ((ub >> 16) & 1u)) >> 16;
    return ua | (ub << 16);
}
__device__ inline unsigned cvt2(float a, float b) { return pack_bf16(a, b); }
__device__ inline ushort bf16_1(float a) { return (ushort)(pack_bf16(a, 0.f) & 0xffffu); }

// fp16 bias chunk base (in fp16 elems) for (bh, q16) where q16 = 16-row slice
// base: chunk lives at the byte address of attn[bh][q16][0] (fp32), i.e.
// fp16 elem offset = 2 * fp32 elem offset. Chunk = 16*512 fp16 = 16 KiB,
// wave's attn write = 32 KiB from same start -> chunk is its first half.
__device__ __host__ inline size_t bias_chunk_base(int bh, int q16) {
    return 2 * (((size_t)bh * SLEN + (size_t)q16) * SLEN);
}

// ---------------------------------------------------------------------------
// bf16 MFMA GEMM: C[m][n] = sum_k X[m][k]*W[n][k] + bias[n]
// BM=64, BN=128, BK=64; 256 threads (4 waves 2x2), wave owns 32x64.
// LDS tiles [row][64 bf16] (128B rows), 16B-slot XOR swizzle: slot ^= row&7.
// MODE 1: fp32 X -> bf16 per-head out[bh][s][64]
// MODE 2: fp32 X -> bf16 transposed out[bh][64][s]
// MODE 3: bf16 X -> fp32 out[m*512+n]
// ---------------------------------------------------------------------------
template<int MODE>
__global__ __launch_bounds__(256) void gemm_bf16(
    const void* __restrict__ Xv, const float* __restrict__ W,
    const float* __restrict__ bias, void* __restrict__ outv)
{
    __shared__ alignas(16) ushort Atile[64 * 64];    // 8 KB
    __shared__ alignas(16) ushort Btile[128 * 64];   // 16 KB

    const float*  Xf = (const float*)Xv;
    const ushort* Xb = (const ushort*)Xv;

    const int tid = threadIdx.x;
    const int wave = tid >> 6, lane = tid & 63;
    const int lq = lane & 15, lg = lane >> 4;
    const int wr = wave >> 1, wc = wave & 1;
    const int m0 = blockIdx.x * 64;
    const int n0 = blockIdx.y * 128;

    f32x4 acc[2][4];
#pragma unroll
    for (int i = 0; i < 2; ++i)
#pragma unroll
        for (int j = 0; j < 4; ++j) acc[i][j] = (f32x4){0.f, 0.f, 0.f, 0.f};

    float4 pa[2][2], pb[4][2];
    uint4  qa[2];

#define LOAD_A(K0)                                                              \
    if (MODE == 3) {                                                            \
        _Pragma("unroll")                                                       \
        for (int i = 0; i < 2; ++i) {                                           \
            const int P = tid + 256 * i;                                        \
            const int row = P >> 3, sl = P & 7;                                 \
            qa[i] = *(const uint4*)&Xb[(size_t)(m0 + row) * 512 + (K0) + sl * 8]; \
        }                                                                       \
    } else {                                                                    \
        _Pragma("unroll")                                                       \
        for (int i = 0; i < 2; ++i) {                                           \
            const int P = tid + 256 * i;                                        \
            const int row = P >> 3, cp = P & 7;                                 \
            const float4* s = (const float4*)&Xf[(size_t)(m0 + row) * 512 + (K0) + cp * 8]; \
            pa[i][0] = s[0]; pa[i][1] = s[1];                                   \
        }                                                                       \
    }
#define LOAD_B(K0)                                                              \
    _Pragma("unroll")                                                           \
    for (int i = 0; i < 4; ++i) {                                               \
        const int P = tid + 256 * i;                                            \
        const int row = P >> 3, cp = P & 7;                                     \
        const float4* s = (const float4*)&W[(size_t)(n0 + row) * 512 + (K0) + cp * 8]; \
        pb[i][0] = s[0]; pb[i][1] = s[1];                                       \
    }

    LOAD_A(0)
    LOAD_B(0)

    for (int it = 0; it < 8; ++it) {
        __syncthreads();
        if (MODE == 3) {
#pragma unroll
            for (int i = 0; i < 2; ++i) {
                const int P = tid + 256 * i;
                const int row = P >> 3, sl = P & 7;
                *(uint4*)((char*)Atile + row * 128 + 16 * (sl ^ (row & 7))) = qa[i];
            }
        } else {
#pragma unroll
            for (int i = 0; i < 2; ++i) {
                const int P = tid + 256 * i;
                const int row = P >> 3, cp = P & 7;
                uint4 w;
                w.x = cvt2(pa[i][0].x, pa[i][0].y);
                w.y = cvt2(pa[i][0].z, pa[i][0].w);
                w.z = cvt2(pa[i][1].x, pa[i][1].y);
                w.w = cvt2(pa[i][1].z, pa[i][1].w);
                *(uint4*)((char*)Atile + row * 128 + 16 * (cp ^ (row & 7))) = w;
            }
        }
#pragma unroll
        for (int i = 0; i < 4; ++i) {
            const int P = tid + 256 * i;
            const int row = P >> 3, cp = P & 7;
            uint4 w;
            w.x = cvt2(pb[i][0].x, pb[i][0].y);
            w.y = cvt2(pb[i][0].z, pb[i][0].w);
            w.z = cvt2(pb[i][1].x, pb[i][1].y);
            w.w = cvt2(pb[i][1].z, pb[i][1].w);
            *(uint4*)((char*)Btile + row * 128 + 16 * (cp ^ (row & 7))) = w;
        }
        __syncthreads();

        if (it < 7) {
            const int kn = (it + 1) * 64;
            LOAD_A(kn)
            LOAD_B(kn)
        }

        short8 af[2][2], bfr[4][2];
#pragma unroll
        for (int mi = 0; mi < 2; ++mi)
#pragma unroll
            for (int kh = 0; kh < 2; ++kh) {
                const int row = wr * 32 + mi * 16 + lq;
                af[mi][kh] = *(const short8*)((const char*)Atile + row * 128 +
                                              16 * ((kh * 4 + lg) ^ (row & 7)));
            }
#pragma unroll
        for (int ni = 0; ni < 4; ++ni)
#pragma unroll
            for (int kh = 0; kh < 2; ++kh) {
                const int row = wc * 64 + ni * 16 + lq;
                bfr[ni][kh] = *(const short8*)((const char*)Btile + row * 128 +
                                               16 * ((kh * 4 + lg) ^ (row & 7)));
            }
        __builtin_amdgcn_s_setprio(1);
#pragma unroll
        for (int kh = 0; kh < 2; ++kh)
#pragma unroll
            for (int mi = 0; mi < 2; ++mi)
#pragma unroll
                for (int ni = 0; ni < 4; ++ni)
                    acc[mi][ni] = __builtin_amdgcn_mfma_f32_16x16x32_bf16(
                        af[mi][kh], bfr[ni][kh], acc[mi][ni], 0, 0, 0);
        __builtin_amdgcn_s_setprio(0);
    }
#undef LOAD_A
#undef LOAD_B

    // ---- epilogue ----
    if (MODE == 3) {
        float* out = (float*)outv;
#pragma unroll
        for (int mi = 0; mi < 2; ++mi) {
            const int mb = m0 + wr * 32 + mi * 16 + lg * 4;
#pragma unroll
            for (int ni = 0; ni < 4; ++ni) {
                const int n = n0 + wc * 64 + ni * 16 + lq;
                const float bb = bias[n];
#pragma unroll
                for (int r = 0; r < 4; ++r)
                    out[(size_t)(mb + r) * 512 + n] = acc[mi][ni][r] + bb;
            }
        }
    } else if (MODE == 1) {
        ushort* out = (ushort*)outv;
#pragma unroll
        for (int mi = 0; mi < 2; ++mi) {
            const int mb = m0 + wr * 32 + mi * 16 + lg * 4;
#pragma unroll
            for (int ni = 0; ni < 4; ++ni) {
                const int n = n0 + wc * 64 + ni * 16 + lq;
                const int h = n >> 6, d = n & 63;
                const float bb = bias[n];
#pragma unroll
                for (int r = 0; r < 4; ++r) {
                    const int m = mb + r;
                    const int bidx = m >> 9, s = m & 511;
                    out[((size_t)(bidx * NH + h) * SLEN + s) * DK + d] =
                        bf16_1(acc[mi][ni][r] + bb);
                }
            }
        }
    } else {
        ushort* out = (ushort*)outv;
#pragma unroll
        for (int mi = 0; mi < 2; ++mi) {
            const int mb = m0 + wr * 32 + mi * 16 + lg * 4;
            const int bidx = mb >> 9, s0 = mb & 511;
#pragma unroll
            for (int ni = 0; ni < 4; ++ni) {
                const int n = n0 + wc * 64 + ni * 16 + lq;
                const int h = n >> 6, d = n & 63;
                const float bb = bias[n];
                uint2 pk;
                pk.x = cvt2(acc[mi][ni][0] + bb, acc[mi][ni][1] + bb);
                pk.y = cvt2(acc[mi][ni][2] + bb, acc[mi][ni][3] + bb);
                *(uint2*)&out[((size_t)(bidx * NH + h) * DK + d) * SLEN + s0] = pk;
            }
        }
    }
}

// ---------------------------------------------------------------------------
// Bias: bias[b,h,q,k] = sum_c dtw[b,c,q,k]*Wd[h,c] + bd[h] -> fp16, written
// in per-(bh, 16-q-row-slice) chunks at the byte address of attn[bh][q&~15][0].
// Each chunk is read only by the attn wave that later overwrites those bytes.
// ---------------------------------------------------------------------------
__global__ __launch_bounds__(512) void bias_kernel(
    const float* __restrict__ dtw, const float* __restrict__ Wd,
    const float* __restrict__ bd, _Float16* __restrict__ bias16)
{
    __shared__ float wdl[NH * DC];
    __shared__ float bdl[NH];
    const int k = threadIdx.x;
    const int q = blockIdx.x;
    const int b = blockIdx.y;
    if (k < NH * DC) wdl[k] = Wd[k];
    if (k < NH) bdl[k] = bd[k];
    __syncthreads();

    float acc[NH];
#pragma unroll
    for (int h = 0; h < NH; ++h) acc[h] = bdl[h];

    const float* p = dtw + ((size_t)b * DC * SLEN + q) * SLEN + k;
#pragma unroll
    for (int c = 0; c < DC; ++c) {
        const float x = p[(size_t)c * SLEN * SLEN];
#pragma unroll
        for (int h = 0; h < NH; ++h) acc[h] += x * wdl[h * DC + c];
    }
    const int q16 = q & ~15, ql = q & 15;
#pragma unroll
    for (int h = 0; h < NH; ++h) {
        const size_t base = bias_chunk_base(b * NH + h, q16);
        bias16[base + (size_t)ql * SLEN + k] = (_Float16)acc[h];
    }
}

// ---------------------------------------------------------------------------
// MFMA attention. 1D grid of 1024 blocks, XCD-swizzled so the 8 q-tile
// blocks sharing one (b,h)'s K/V dispatch back-to-back on one XCD.
// Bias is read from the first 16 KiB of each wave's own attn write range
// (all reads land in registers before any attn store issues -> race-free).
// ---------------------------------------------------------------------------
__global__ __launch_bounds__(256, 2) void attn_mfma(
    const ushort* __restrict__ qb, const ushort* __restrict__ kb,
    const ushort* __restrict__ vt, float* __restrict__ attn,
    ushort* __restrict__ concat)
{
    __shared__ ushort P_lds[4][16][512];   // 64 KB, per-wave private

    const int tid = threadIdx.x;
    const int wave = tid >> 6;
    const int lane = tid & 63;
    const int lq = lane & 15;
    const int lg = lane >> 4;

    // XCD swizzle: l&7 = XCD; 8 consecutive dispatches on an XCD = one (b,h)
    const unsigned l = blockIdx.x;
    const int g  = (int)((l & 7) + 8 * (l >> 6));   // (b,h) group 0..127
    const int qt = (int)((l >> 3) & 7);             // q-tile within group
    const int h = g & 7, b = g >> 3;
    const int bh = b * NH + h;
    const int q0 = qt * 64 + wave * 16;

    const ushort* qptr = qb + ((size_t)bh * SLEN + q0) * DK;
    const ushort* kptr = kb + (size_t)bh * SLEN * DK;
    const ushort* vptr = vt + (size_t)bh * DK * SLEN;
    float* attn_b = attn + ((size_t)bh * SLEN + q0) * SLEN;
    const _Float16* bias_row =
        (const _Float16*)attn + bias_chunk_base(bh, q0) + (size_t)lq * SLEN;

    const short8 qf0 = *(const short8*)&qptr[(size_t)lq * DK + lg * 8];
    const short8 qf1 = *(const short8*)&qptr[(size_t)lq * DK + lg * 8 + 32];

    f32x4 sc[32];
#pragma unroll
    for (int kt = 0; kt < 32; ++kt) {
        const short8 a0 = *(const short8*)&kptr[(size_t)(kt * 16 + lq) * DK + lg * 8];
        const short8 a1 = *(const short8*)&kptr[(size_t)(kt * 16 + lq) * DK + lg * 8 + 32];
        f32x4 c = {0.f, 0.f, 0.f, 0.f};
        __builtin_amdgcn_s_setprio(1);
        c = __builtin_amdgcn_mfma_f32_16x16x32_bf16(a0, qf0, c, 0, 0, 0);
        c = __builtin_amdgcn_mfma_f32_16x16x32_bf16(a1, qf1, c, 0, 0, 0);
        __builtin_amdgcn_s_setprio(0);
        const h16x4 bh4 = *(const h16x4*)&bias_row[kt * 16 + lg * 4];
        f32x4 bias4;
        bias4[0] = (float)bh4[0]; bias4[1] = (float)bh4[1];
        bias4[2] = (float)bh4[2]; bias4[3] = (float)bh4[3];
        sc[kt] = c * 0.125f + bias4;
    }

    float m = -1e30f;
#pragma unroll
    for (int kt = 0; kt < 32; ++kt)
        m = fmaxf(m, fmaxf(fmaxf(sc[kt][0], sc[kt][1]), fmaxf(sc[kt][2], sc[kt][3])));
    m = fmaxf(m, __shfl_xor(m, 16));
    m = fmaxf(m, __shfl_xor(m, 32));

    float sum = 0.f;
#pragma unroll
    for (int kt = 0; kt < 32; ++kt) {
        f32x4 e;
        e[0] = __expf(sc[kt][0] - m);
        e[1] = __expf(sc[kt][1] - m);
        e[2] = __expf(sc[kt][2] - m);
        e[3] = __expf(sc[kt][3] - m);
        sum += (e[0] + e[1]) + (e[2] + e[3]);
        sc[kt] = e;
    }
    sum += __shfl_xor(sum, 16);
    sum += __shfl_xor(sum, 32);
    const float inv = 1.0f / sum;

    char* pbase = (char*)&P_lds[wave][0][0];
    const unsigned swz = (unsigned)((lq & 7) << 4);
#pragma unroll
    for (int kt = 0; kt < 32; ++kt) {
        const f32x4 e = sc[kt];
        f32x4 a4 = e * inv;
        *(f32x4*)&attn_b[(size_t)lq * SLEN + kt * 16 + lg * 4] = a4;
        uint2 pk;
        pk.x = pack_bf16(e[0], e[1]);
        pk.y = pack_bf16(e[2], e[3]);
        const unsigned byte = (unsigned)(lq * 1024 + kt * 32 + lg * 8) ^ swz;
        *(uint2*)(pbase + byte) = pk;
    }
    asm volatile("s_waitcnt lgkmcnt(0)" ::: "memory");
    __builtin_amdgcn_sched_barrier(0);

    f32x4 oacc[4] = {{0.f,0.f,0.f,0.f},{0.f,0.f,0.f,0.f},{0.f,0.f,0.f,0.f},{0.f,0.f,0.f,0.f}};
#pragma unroll
    for (int c = 0; c < 16; ++c) {
        const unsigned byteA = (unsigned)(lq * 1024 + c * 64 + lg * 16) ^ swz;
        const short8 pa = *(const short8*)(pbase + byteA);
        __builtin_amdgcn_s_setprio(1);
#pragma unroll
        for (int dt = 0; dt < 4; ++dt) {
            const short8 vb8 = *(const short8*)&vptr[(size_t)(dt * 16 + lq) * SLEN + c * 32 + lg * 8];
            oacc[dt] = __builtin_amdgcn_mfma_f32_16x16x32_bf16(pa, vb8, oacc[dt], 0, 0, 0);
        }
        __builtin_amdgcn_s_setprio(0);
    }

    // concat in bf16 [b][s][h*64+d]
    ushort* cbase = concat + ((size_t)(b * SLEN + q0)) * DM + h * 64;
#pragma unroll
    for (int r = 0; r < 4; ++r) {
        const float iv = __shfl(inv, lg * 4 + r);
#pragma unroll
        for (int dt = 0; dt < 4; ++dt) {
            cbase[(size_t)(lg * 4 + r) * DM + dt * 16 + lq] = bf16_1(oacc[dt][r] * iv);
        }
    }
}

// ---------------------------------------------------------------------------
extern "C" void kernel_launch(void* const* d_in, const int* in_sizes, int n_in,
                              void* d_out, int out_size, void* d_ws, size_t ws_size,
                              hipStream_t stream)
{
    const float* Q   = (const float*)d_in[0];
    const float* K   = (const float*)d_in[1];
    const float* V   = (const float*)d_in[2];
    const float* dtw = (const float*)d_in[4];
    const float* Wq  = (const float*)d_in[5];
    const float* bq  = (const float*)d_in[6];
    const float* Wk  = (const float*)d_in[7];
    const float* bk  = (const float*)d_in[8];
    const float* Wv  = (const float*)d_in[9];
    const float* bv  = (const float*)d_in[10];
    const float* Wd  = (const float*)d_in[11];
    const float* bd  = (const float*)d_in[12];
    const float* Wo  = (const float*)d_in[13];
    const float* bo  = (const float*)d_in[14];

    float* out  = (float*)d_out;                       // [16,512,512] fp32
    float* attn = out + (size_t)BS * SLEN * DM;        // [16,8,512,512] fp32
    _Float16* bias16 = (_Float16*)attn;                // fp16 bias chunks inside attn region

    const size_t PHS = (size_t)BS * NH * SLEN * DK;    // 4,194,304 elements
    ushort* qb = (ushort*)d_ws;
    ushort* kb = qb + PHS;
    ushort* vt = kb + PHS;
    ushort* cb = vt + PHS;                             // concat bf16 [16,512,512]

    const dim3 gemm_grid(128, 4);                      // m-tiles x n-tiles

    gemm_bf16<1><<<gemm_grid, 256, 0, stream>>>(Q, Wq, bq, qb);
    gemm_bf16<1><<<gemm_grid, 256, 0, stream>>>(K, Wk, bk, kb);
    gemm_bf16<2><<<gemm_grid, 256, 0, stream>>>(V, Wv, bv, vt);

    bias_kernel<<<dim3(SLEN, BS), 512, 0, stream>>>(dtw, Wd, bd, bias16);

    attn_mfma<<<dim3(1024), 256, 0, stream>>>(qb, kb, vt, attn, cb);

    gemm_bf16<3><<<gemm_grid, 256, 0, stream>>>(cb, Wo, bo, out);
}